// Round 9
// baseline (1526.220 us; speedup 1.0000x reference)
//
#include <hip/hip_runtime.h>

// ---------------------------------------------------------------------------
// SDGL gcn_module: out = W1*x + W2*(G1 x) + W3*(G2 x) + b
//   G1 = AL^2 + AS - AS*AL ; G2 = AL^3 + AS^2 - AS2*AL   (per-slice linear op)
// KEY: channel-mix commutes with graph ops: W2*(G1 x) = G1*(W2 x).
// Pipeline: prep(AL,AS) -> 5 pre-GEMMs -> assemble Gcat[1024][2048] (+W cast)
//   -> k_mix_g (x -> Yc planes [W1x|W2x|W3x], zero write-amp) -> fused graph
//   GEMM out = Gcat @ [W2x|W3x]^T + W1x + bias  (M=1024,N=32768,K=2048).
// R9 main GEMM: BK=32, LDS 64 KiB -> TWO blocks/CU (16 waves/CU).  R5/R7/R8
//   proved the intra-block schedule is not the binder (3 structurally
//   different schedules all ~165us / 35% MfmaUtil at 1 block/CU): with one
//   resident block, every barrier/vmcnt stall idles the whole CU.  m114/m97
//   evidence: co-resident blocks absorb exactly this (implicit overlap).
//   2 phases/tile x 16 independent MFMA (no acc kk-chain); 1 gload/thread
//   per half-tile; 4-chunk row swizzle phys=c^(row&3) (both sides); stage
//   into cur only after the barrier that sequenced all waves' reads of that
//   region; counted vmcnt(2) per tile (B(t+2) stays in flight).
// ---------------------------------------------------------------------------

typedef __bf16 bf16x8 __attribute__((ext_vector_type(8)));
typedef float f32x4 __attribute__((ext_vector_type(4)));
typedef unsigned int u32x4 __attribute__((ext_vector_type(4)));
typedef unsigned int u32x2 __attribute__((ext_vector_type(2)));

__device__ __forceinline__ unsigned short f2bf(float f) {
  unsigned u = __builtin_bit_cast(unsigned, f);
  u += 0x7fffu + ((u >> 16) & 1u);           // round-to-nearest-even
  return (unsigned short)(u >> 16);
}
__device__ __forceinline__ float bf2f(unsigned short h) {
  unsigned u = ((unsigned)h) << 16;
  return __builtin_bit_cast(float, u);
}

// ---------------- workspace layout (bytes) ----------------
static constexpr size_t OFF_YC    = 0;                      // 384*32768*8*2 = 192 MiB
static constexpr size_t OFF_ALBF  = 201326592;              // each small mat 2 MiB
static constexpr size_t OFF_ALT   = OFF_ALBF  + 2097152;
static constexpr size_t OFF_ASBF  = OFF_ALT   + 2097152;
static constexpr size_t OFF_AST   = OFF_ASBF  + 2097152;
static constexpr size_t OFF_AL2   = OFF_AST   + 2097152;
static constexpr size_t OFF_AL2T  = OFF_AL2   + 2097152;    // unused (layout keep)
static constexpr size_t OFF_ASAL  = OFF_AL2T  + 2097152;
static constexpr size_t OFF_AS2   = OFF_ASAL  + 2097152;
static constexpr size_t OFF_AL3   = OFF_AS2   + 2097152;
static constexpr size_t OFF_AS2AL = OFF_AL3   + 2097152;
static constexpr size_t OFF_G     = OFF_AS2AL + 2097152;    // 1024*2048*2 = 4 MiB
// Wall (96x32 bf16, 6 KiB) reuses OFF_ALBF after pre-GEMM stage0 retires ALbf.

// ---------------- k_prep: fp32 [1024][1024] -> bf16 natural + transposed ----
// z = 0: AL, z = 1: AS (merged launch).
__global__ __launch_bounds__(256) void k_prep(const float* __restrict__ AL,
                                              const float* __restrict__ AS,
                                              unsigned short* __restrict__ ALn,
                                              unsigned short* __restrict__ ALtr,
                                              unsigned short* __restrict__ ASn,
                                              unsigned short* __restrict__ AStr) {
  const float* src = blockIdx.z ? AS : AL;
  unsigned short* dstN = blockIdx.z ? ASn : ALn;
  unsigned short* dstT = blockIdx.z ? AStr : ALtr;
  __shared__ float Xs[64][65];
  const int tid = threadIdx.x;
  const int r0 = blockIdx.x * 64, c0 = blockIdx.y * 64;
  const int lrow = tid >> 4, lc4 = tid & 15;
#pragma unroll
  for (int rr = 0; rr < 4; rr++) {
    int row = rr * 16 + lrow;
    float4 v = *(const float4*)(src + (size_t)(r0 + row) * 1024 + c0 + lc4 * 4);
    Xs[row][lc4 * 4 + 0] = v.x;
    Xs[row][lc4 * 4 + 1] = v.y;
    Xs[row][lc4 * 4 + 2] = v.z;
    Xs[row][lc4 * 4 + 3] = v.w;
    unsigned lo = (unsigned)f2bf(v.x) | ((unsigned)f2bf(v.y) << 16);
    unsigned hi = (unsigned)f2bf(v.z) | ((unsigned)f2bf(v.w) << 16);
    u32x2 pk = {lo, hi};
    *(u32x2*)(dstN + (size_t)(r0 + row) * 1024 + c0 + lc4 * 4) = pk;
  }
  __syncthreads();
  const int wc = tid & 7;
#pragma unroll
  for (int u = 0; u < 2; u++) {
    int t = u * 32 + (tid >> 3);
    unsigned v0 = (unsigned)f2bf(Xs[wc * 8 + 0][t]) | ((unsigned)f2bf(Xs[wc * 8 + 1][t]) << 16);
    unsigned v1 = (unsigned)f2bf(Xs[wc * 8 + 2][t]) | ((unsigned)f2bf(Xs[wc * 8 + 3][t]) << 16);
    unsigned v2 = (unsigned)f2bf(Xs[wc * 8 + 4][t]) | ((unsigned)f2bf(Xs[wc * 8 + 5][t]) << 16);
    unsigned v3 = (unsigned)f2bf(Xs[wc * 8 + 6][t]) | ((unsigned)f2bf(Xs[wc * 8 + 7][t]) << 16);
    u32x4 pk = {v0, v1, v2, v3};
    *(u32x4*)(dstT + (size_t)(c0 + t) * 1024 + r0 + wc * 8) = pk;
  }
}

// ---------------- core 128x128 bf16 GEMM, C = A * Bt^T (pre-GEMMs) ----------
__device__ __forceinline__ void gemm128_bt(const unsigned short* __restrict__ A,
                                           const unsigned short* __restrict__ Bt,
                                           unsigned short* __restrict__ Cp,
                                           int K, size_t ldc, int m0, int n0) {
  __shared__ unsigned short As[128 * 32];
  __shared__ unsigned short Bs[128 * 32];
  const int tid = threadIdx.x;
  const int wave = tid >> 6, lane = tid & 63;
  const int lane15 = lane & 15, quad = lane >> 4;
  const int wm = wave & 1, wn = wave >> 1;
  const int srow = lane >> 2;
  const int schunk = (lane & 3) * 8;

  const unsigned short* gA0 = A + (size_t)(m0 + wave * 16 + srow) * K + schunk;
  const unsigned short* gA1 = A + (size_t)(m0 + 64 + wave * 16 + srow) * K + schunk;
  const unsigned short* gB0 = Bt + (size_t)(n0 + wave * 16 + srow) * K + schunk;
  const unsigned short* gB1 = Bt + (size_t)(n0 + 64 + wave * 16 + srow) * K + schunk;
  unsigned short* lA0 = As + (wave * 16) * 32;
  unsigned short* lA1 = As + (64 + wave * 16) * 32;
  unsigned short* lB0 = Bs + (wave * 16) * 32;
  unsigned short* lB1 = Bs + (64 + wave * 16) * 32;

  f32x4 acc[4][4];
#pragma unroll
  for (int i = 0; i < 4; i++)
#pragma unroll
    for (int j = 0; j < 4; j++) acc[i][j] = (f32x4){0.f, 0.f, 0.f, 0.f};

  const unsigned short* pa = As + (wm * 64 + lane15) * 32 + quad * 8;
  const unsigned short* pb = Bs + (wn * 64 + lane15) * 32 + quad * 8;

  for (int kb = 0; kb < K; kb += 32) {
    __syncthreads();
    __builtin_amdgcn_global_load_lds(
        (const __attribute__((address_space(1))) unsigned int*)(gA0 + kb),
        (__attribute__((address_space(3))) unsigned int*)lA0, 16, 0, 0);
    __builtin_amdgcn_global_load_lds(
        (const __attribute__((address_space(1))) unsigned int*)(gA1 + kb),
        (__attribute__((address_space(3))) unsigned int*)lA1, 16, 0, 0);
    __builtin_amdgcn_global_load_lds(
        (const __attribute__((address_space(1))) unsigned int*)(gB0 + kb),
        (__attribute__((address_space(3))) unsigned int*)lB0, 16, 0, 0);
    __builtin_amdgcn_global_load_lds(
        (const __attribute__((address_space(1))) unsigned int*)(gB1 + kb),
        (__attribute__((address_space(3))) unsigned int*)lB1, 16, 0, 0);
    __syncthreads();

    bf16x8 av[4], bv[4];
#pragma unroll
    for (int mt = 0; mt < 4; mt++) av[mt] = *(const bf16x8*)(pa + mt * 16 * 32);
#pragma unroll
    for (int nt = 0; nt < 4; nt++) bv[nt] = *(const bf16x8*)(pb + nt * 16 * 32);
#pragma unroll
    for (int mt = 0; mt < 4; mt++)
#pragma unroll
      for (int nt = 0; nt < 4; nt++)
        acc[mt][nt] = __builtin_amdgcn_mfma_f32_16x16x32_bf16(av[mt], bv[nt], acc[mt][nt], 0, 0, 0);
  }

#pragma unroll
  for (int mt = 0; mt < 4; mt++) {
#pragma unroll
    for (int nt = 0; nt < 4; nt++) {
      const int col = n0 + wn * 64 + nt * 16 + lane15;
#pragma unroll
      for (int r = 0; r < 4; r++) {
        const int row = m0 + wm * 64 + mt * 16 + quad * 4 + r;
        Cp[(size_t)row * ldc + col] = f2bf(acc[mt][nt][r]);
      }
    }
  }
}

// ---------------- G-precompute GEMMs (batched by z; 5 total) ----------------
__global__ __launch_bounds__(256) void k_gemm_pre(char* ws, int stage) {
  const unsigned short* A;
  const unsigned short* Bt;
  unsigned short* Cp;
  const int z = blockIdx.z;
  unsigned short* ALbf = (unsigned short*)(ws + OFF_ALBF);
  unsigned short* ALt  = (unsigned short*)(ws + OFF_ALT);
  unsigned short* ASbf = (unsigned short*)(ws + OFF_ASBF);
  unsigned short* ASt  = (unsigned short*)(ws + OFF_AST);
  unsigned short* AL2  = (unsigned short*)(ws + OFF_AL2);
  unsigned short* ASAL = (unsigned short*)(ws + OFF_ASAL);
  unsigned short* AS2  = (unsigned short*)(ws + OFF_AS2);
  unsigned short* AL3  = (unsigned short*)(ws + OFF_AL3);
  unsigned short* AS2AL= (unsigned short*)(ws + OFF_AS2AL);
  if (stage == 0) {
    if (z == 0)      { A = ALbf; Bt = ALt;  Cp = AL2;  }   // AL^2
    else if (z == 1) { A = ASbf; Bt = ALt;  Cp = ASAL; }   // AS*AL
    else             { A = ASbf; Bt = ASt;  Cp = AS2;  }   // AS^2
  } else {
    if (z == 0)      { A = AL2;  Bt = ALt;  Cp = AL3;  }   // AL^2*AL = AL^3
    else             { A = AS2;  Bt = ALt;  Cp = AS2AL;}   // AS^2*AL
  }
  gemm128_bt(A, Bt, Cp, 1024, 1024, blockIdx.y * 128, blockIdx.x * 128);
}

// ---------------- assemble Gcat[1024][2048] = [G1 | G2] bf16 (+W cast) ------
__global__ __launch_bounds__(256) void k_assemble_G(const unsigned short* __restrict__ AL2,
                                                    const unsigned short* __restrict__ ASAL,
                                                    const float* __restrict__ ASf,
                                                    const unsigned short* __restrict__ AL3,
                                                    const unsigned short* __restrict__ AS2,
                                                    const unsigned short* __restrict__ AS2AL,
                                                    const float* __restrict__ W,
                                                    unsigned short* __restrict__ Wall,
                                                    unsigned short* __restrict__ G) {
  if (blockIdx.x == 0) {   // fold W -> Wall[g*32+o][c] cast into block 0
    for (int k = threadIdx.x; k < 3072; k += 256) {
      int oo = k >> 5, c = k & 31;
      Wall[k] = f2bf(W[(oo & 31) * 96 + (oo >> 5) * 32 + c]);
    }
  }
  int i = blockIdx.x * 256 + threadIdx.x;           // over 1024*1024
  int r = i >> 10, c = i & 1023;
  float g1 = bf2f(AL2[i]) + ASf[i] - bf2f(ASAL[i]);
  float g2 = bf2f(AL3[i]) + bf2f(AS2[i]) - bf2f(AS2AL[i]);
  G[(size_t)r * 2048 + c]        = f2bf(g1);
  G[(size_t)r * 2048 + 1024 + c] = f2bf(g2);
}

// ---------------- k_mix_g: channel mix via MFMA (K=32) ----------------
// Output Yc[G][j][8] planes, G = og*128 + n8 (j = (b,o,t)).  grid 2048 =
// 16 b x 128 n8 (8 n each), 256 thr / 4 waves (t-quads), XCD-chunked decode.
// Stores: 16B granules, quad = 256B contiguous -> zero write amplification.
__global__ __launch_bounds__(256, 8) void k_mix_g(const float* __restrict__ x,
                                                  const unsigned short* __restrict__ Wall,
                                                  unsigned short* __restrict__ Yc) {
  const int tid = threadIdx.x;
  const int sid = (blockIdx.x & 7) * 256 + (blockIdx.x >> 3);
  const int b   = sid >> 7;
  const int n8g = sid & 127;
  const int nbase = n8g * 8;
  const int wave = tid >> 6, lane = tid & 63;
  const int lane15 = lane & 15, quad = lane >> 4;
  const int t = wave * 16 + lane15;

  bf16x8 afr[6];
#pragma unroll
  for (int ot = 0; ot < 6; ot++)
    afr[ot] = *(const bf16x8*)(Wall + (ot * 16 + lane15) * 32 + quad * 8);

  const float* xb = x + (size_t)b * 2097152 + (size_t)(quad * 8) * 65536 + t;

  bf16x8 bfr[8];
#pragma unroll
  for (int nl = 0; nl < 8; nl++) {
    const float* xp = xb + (size_t)(nbase + nl) * 64;
    unsigned u[4];
#pragma unroll
    for (int e = 0; e < 4; e++) {
      float a  = xp[(size_t)(2 * e) * 65536];
      float c2 = xp[(size_t)(2 * e + 1) * 65536];
      u[e] = (unsigned)f2bf(a) | ((unsigned)f2bf(c2) << 16);
    }
    u32x4 pk = {u[0], u[1], u[2], u[3]};
    bfr[nl] = __builtin_bit_cast(bf16x8, pk);
  }

#pragma unroll
  for (int ot = 0; ot < 6; ot++) {
    f32x4 acc[8];
    const f32x4 z = (f32x4){0.f, 0.f, 0.f, 0.f};
#pragma unroll
    for (int nl = 0; nl < 8; nl++)
      acc[nl] = __builtin_amdgcn_mfma_f32_16x16x32_bf16(afr[ot], bfr[nl], z, 0, 0, 0);
    const int og = ot >> 1;                       // 0:W1x 1:W2x 2:W3x
    const int o  = (ot & 1) * 16 + quad * 4;      // + r
    const size_t plane = (size_t)(og * 128 + n8g) * 262144;
#pragma unroll
    for (int r = 0; r < 4; r++) {
      unsigned u0 = (unsigned)f2bf(acc[0][r]) | ((unsigned)f2bf(acc[1][r]) << 16);
      unsigned u1 = (unsigned)f2bf(acc[2][r]) | ((unsigned)f2bf(acc[3][r]) << 16);
      unsigned u2 = (unsigned)f2bf(acc[4][r]) | ((unsigned)f2bf(acc[5][r]) << 16);
      unsigned u3 = (unsigned)f2bf(acc[6][r]) | ((unsigned)f2bf(acc[7][r]) << 16);
      u32x4 pk = {u0, u1, u2, u3};
      size_t j = (size_t)(b * 32 + o + r) * 64 + t;
      *(u32x4*)(Yc + plane + j * 8) = pk;
    }
  }
}

// ---------------- main GEMM: out = Gcat @ [W2x|W3x]^T + W1x + bias ----------
// M=1024, N=32768, K=2048 (64 K-tiles of BK=32). 512 blocks x 512 thr.
// LDS 64 KiB (2 blocks/CU): [A0 16K][B0 16K][A1 16K][B1 16K]; each buffer =
// 2 halves x 128 rows x 32 shorts.  2 phases/tile x 16 independent MFMA.
// Swizzle: phys chunk = c ^ (row&3) on stage source AND ds_read (both-sides).
// WAR safety: a stage into cur is issued only after the barrier that follows
// the lgkmcnt(0) of the phase whose reads covered that region (sequenced).
__global__ __launch_bounds__(512, 4) void k_gemm_main8(const unsigned short* __restrict__ A,
                                                       const unsigned short* __restrict__ Yc,
                                                       const float* __restrict__ bm,
                                                       float* __restrict__ out) {
  __shared__ unsigned short lds[32768];   // 64 KiB
  const int tid = threadIdx.x;
  const int wave = tid >> 6, lane = tid & 63;
  const int lane15 = lane & 15, quad = lane >> 4;
  const int wr = wave >> 2, wc = wave & 3;          // 2M x 4N

  const int bid = blockIdx.x;
  const int swz = (bid & 7) * 64 + (bid >> 3);      // XCD-bijective (512%8==0)
  const int nx = swz >> 2, my = swz & 3;            // 128 N-tiles x 4 M-tiles
  const int m0 = my * 256, n0 = nx * 256;

  const int srow = tid >> 2;                          // 0..127
  const int cswz = (tid & 3) ^ (srow & 3);            // swizzled k-chunk 0..3
  const int ldst0 = tid * 8;                          // shorts (16B per thread)

#define STAGE_A32(rowbase, dsthalf, ktile)                                              \
  do {                                                                                 \
    const unsigned short* _g =                                                         \
        A + (size_t)((rowbase) + srow) * 2048 + (size_t)((ktile) * 32 + cswz * 8);     \
    __builtin_amdgcn_global_load_lds(                                                  \
        (const __attribute__((address_space(1))) unsigned int*)_g,                     \
        (__attribute__((address_space(3))) unsigned int*)((dsthalf) + ldst0), 16, 0, 0);\
  } while (0)

#define STAGE_B32(rowbase, dsthalf, ktile)                                              \
  do {                                                                                 \
    const unsigned short* _g = Yc + (size_t)(128 + (ktile) * 4 + cswz) * 262144 +      \
                               (size_t)((rowbase) + srow) * 8;                         \
    __builtin_amdgcn_global_load_lds(                                                  \
        (const __attribute__((address_space(1))) unsigned int*)_g,                     \
        (__attribute__((address_space(3))) unsigned int*)((dsthalf) + ldst0), 16, 0, 0);\
  } while (0)

#define RD_B32()                                                                        \
  _Pragma("unroll") for (int n = 0; n < 4; n++)                                         \
      bfr[n] = *(const bf16x8*)(pB + n * 512 + aks);

#define RD_A32(m0i)                                                                     \
  _Pragma("unroll") for (int mi = 0; mi < 4; mi++)                                      \
      afr[mi] = *(const bf16x8*)(pA + ((m0i) + mi) * 512 + aks);

#define MFMA16(i0)                                                                      \
  _Pragma("unroll") for (int mi = 0; mi < 4; mi++)                                      \
      _Pragma("unroll") for (int n = 0; n < 4; n++)                                     \
          acc[(i0) + mi][n] = __builtin_amdgcn_mfma_f32_16x16x32_bf16(                  \
              afr[mi], bfr[n], acc[(i0) + mi][n], 0, 0, 0);

#define BAR()   asm volatile("" ::: "memory"); __builtin_amdgcn_s_barrier();
#define LGKM0() asm volatile("s_waitcnt lgkmcnt(0)" ::: "memory");                      \
                __builtin_amdgcn_sched_barrier(0);
#define PRIO1() __builtin_amdgcn_s_setprio(1);
#define PRIO0() __builtin_amdgcn_s_setprio(0);

  // LDS layout (shorts): A0 @0, B0 @8192, A1 @16384, B1 @24576; half = +4096.
  unsigned short* Acur = lds;
  unsigned short* Bcur = lds + 8192;
  unsigned short* Aalt = lds + 16384;
  unsigned short* Balt = lds + 24576;

  f32x4 acc[8][4];
#pragma unroll
  for (int i = 0; i < 8; i++)
#pragma unroll
    for (int j = 0; j < 4; j++) acc[i][j] = (f32x4){0.f, 0.f, 0.f, 0.f};

  const int aks = ((quad ^ (lane15 & 3)) << 3);     // read-side swizzled chunk

  bf16x8 bfr[4], afr[4];

  // ---- prologue: tile0 {A0,A1,B0,B1} + tile1 {B0,B1}; vmcnt(2) => tile0 in --
  STAGE_A32(m0,       Acur,        0);
  STAGE_A32(m0 + 128, Acur + 4096, 0);
  STAGE_B32(n0,       Bcur,        0);
  STAGE_B32(n0 + 128, Bcur + 4096, 0);
  STAGE_B32(n0,       Balt,        1);
  STAGE_B32(n0 + 128, Balt + 4096, 1);
  asm volatile("s_waitcnt vmcnt(2)" ::: "memory");
  BAR();

  // ---- main loop: tiles 0..61, 2 phases each ----
  for (int t = 0; t < 62; ++t) {
    const unsigned short* pA = Acur + wr * 4096 + lane15 * 32;
    const unsigned short* pB = Bcur + (wc >> 1) * 4096 + ((wc & 1) * 64 + lane15) * 32;
    // ph1: B(t) all (4) + A(t) m0-3 (4) | stage A0,A1(t+1) -> alt
    RD_B32();
    RD_A32(0);
    STAGE_A32(m0,       Aalt,        t + 1);
    STAGE_A32(m0 + 128, Aalt + 4096, t + 1);
    BAR(); LGKM0();
    PRIO1(); MFMA16(0); PRIO0();
    BAR();
    // ph2: A(t) m4-7 (4) | stage B0,B1(t+2) -> cur (B(t) reads sequenced done)
    RD_A32(4);
    STAGE_B32(n0,       Bcur,        t + 2);
    STAGE_B32(n0 + 128, Bcur + 4096, t + 2);
    BAR(); LGKM0();
    PRIO1(); MFMA16(4); PRIO0();
    asm volatile("s_waitcnt vmcnt(2)" ::: "memory");  // A(t+1) in; B(t+2) flies
    BAR();
    unsigned short* tmp;
    tmp = Acur; Acur = Aalt; Aalt = tmp;
    tmp = Bcur; Bcur = Balt; Balt = tmp;
  }

  // ---- tile 62: stage only A(63); end with full drain ----
  {
    const unsigned short* pA = Acur + wr * 4096 + lane15 * 32;
    const unsigned short* pB = Bcur + (wc >> 1) * 4096 + ((wc & 1) * 64 + lane15) * 32;
    RD_B32();
    RD_A32(0);
    STAGE_A32(m0,       Aalt,        63);
    STAGE_A32(m0 + 128, Aalt + 4096, 63);
    BAR(); LGKM0();
    PRIO1(); MFMA16(0); PRIO0();
    BAR();
    RD_A32(4);
    BAR(); LGKM0();
    PRIO1(); MFMA16(4); PRIO0();
    asm volatile("s_waitcnt vmcnt(0)" ::: "memory");
    BAR();
    unsigned short* tmp;
    tmp = Acur; Acur = Aalt; Aalt = tmp;
    tmp = Bcur; Bcur = Balt; Balt = tmp;
  }

  // ---- tile 63: pure compute ----
  {
    const unsigned short* pA = Acur + wr * 4096 + lane15 * 32;
    const unsigned short* pB = Bcur + (wc >> 1) * 4096 + ((wc & 1) * 64 + lane15) * 32;
    RD_B32();
    RD_A32(0);
    LGKM0();
    MFMA16(0);
    RD_A32(4);
    LGKM0();
    MFMA16(4);
  }

  // ---- fused epilogue: out[b,o,n',t] = acc + W1x + bias (fp32 store) ----
#pragma unroll
  for (int mt = 0; mt < 8; mt++) {
    const int row = m0 + wr * 128 + mt * 16 + quad * 4;
#pragma unroll
    for (int nf = 0; nf < 4; nf++) {
      const int col = n0 + wc * 64 + nf * 16 + lane15;
      const int bo_idx = col >> 6;                    // b*32+o (uniform)
      const float bo = bm[bo_idx & 31];
      const size_t obase = (size_t)bo_idx * 65536 + (col & 63);
      ushort4 yv = *(const ushort4*)(Yc + (size_t)(row >> 3) * 262144 +
                                     (size_t)col * 8 + (row & 7));
      out[obase + (size_t)(row + 0) * 64] = acc[mt][nf][0] + bf2f(yv.x) + bo;
      out[obase + (size_t)(row + 1) * 64] = acc[mt][nf][1] + bf2f(yv.y) + bo;
      out[obase + (size_t)(row + 2) * 64] = acc[mt][nf][2] + bf2f(yv.z) + bo;
      out[obase + (size_t)(row + 3) * 64] = acc[mt][nf][3] + bf2f(yv.w) + bo;
    }
  }
#undef STAGE_A32
#undef STAGE_B32
#undef RD_B32
#undef RD_A32
#undef MFMA16
#undef BAR
#undef LGKM0
#undef PRIO1
#undef PRIO0
}

extern "C" void kernel_launch(void* const* d_in, const int* in_sizes, int n_in,
                              void* d_out, int out_size, void* d_ws, size_t ws_size,
                              hipStream_t stream) {
  const float* x  = (const float*)d_in[0];
  const float* AL = (const float*)d_in[1];
  const float* AS = (const float*)d_in[2];
  const float* W  = (const float*)d_in[3];
  const float* bm = (const float*)d_in[4];
  float* out = (float*)d_out;
  char* ws = (char*)d_ws;

  unsigned short* Yc    = (unsigned short*)(ws + OFF_YC);
  unsigned short* ALbf  = (unsigned short*)(ws + OFF_ALBF);
  unsigned short* ALt   = (unsigned short*)(ws + OFF_ALT);
  unsigned short* ASbf  = (unsigned short*)(ws + OFF_ASBF);
  unsigned short* ASt   = (unsigned short*)(ws + OFF_AST);
  unsigned short* AL2   = (unsigned short*)(ws + OFF_AL2);
  unsigned short* ASAL  = (unsigned short*)(ws + OFF_ASAL);
  unsigned short* AS2   = (unsigned short*)(ws + OFF_AS2);
  unsigned short* AL3   = (unsigned short*)(ws + OFF_AL3);
  unsigned short* AS2AL = (unsigned short*)(ws + OFF_AS2AL);
  unsigned short* Gm    = (unsigned short*)(ws + OFF_G);
  unsigned short* Wall  = (unsigned short*)(ws + OFF_ALBF);  // reused after stage0

  // 1) AL/AS -> bf16 natural + transposed (merged, z = which matrix)
  k_prep<<<dim3(16, 16, 2), 256, 0, stream>>>(AL, AS, ALbf, ALt, ASbf, ASt);
  // 2) G pieces: {AL2, ASAL, AS2} then {AL3, AS2AL}
  k_gemm_pre<<<dim3(8, 8, 3), 256, 0, stream>>>(ws, 0);
  k_gemm_pre<<<dim3(8, 8, 2), 256, 0, stream>>>(ws, 1);
  // 3) assemble Gcat (+ W -> Wall cast folded into block 0)
  k_assemble_G<<<4096, 256, 0, stream>>>(AL2, ASAL, AS, AL3, AS2, AS2AL, W, Wall, Gm);
  // 4) channel mix: x -> Yc planes [W1x | W2x | W3x]
  k_mix_g<<<2048, 256, 0, stream>>>(x, Wall, Yc);
  // 5) fused graph GEMM + epilogue: out = Gcat @ [W2x|W3x]^T + W1x + bias
  k_gemm_main8<<<dim3(512, 1, 1), 512, 0, stream>>>(Gm, Yc, bm, out);
}